// Round 1
// baseline (21.716 us; speedup 1.0000x reference)
//
#include <hip/hip_runtime.h>

// Aggregation (SAN-style): out[n,c,l] = sum_kk input_padded[n,c,tap(l,kk)] * weight[n, c/8, kk, l]
// N=8, C=256, Cw=32, share=8, K=3, H=W=56, L=3136. All fp32.

#define HH 56
#define WW 56
#define LL 3136
#define CW 32
#define SHARE 8
#define CC 256
#define NN 8

__global__ __launch_bounds__(256) void agg_kernel(const float* __restrict__ in,
                                                  const float* __restrict__ wt,
                                                  float* __restrict__ out) {
    const int l = blockIdx.x * 256 + threadIdx.x;
    const int g = blockIdx.y;   // weight-channel group, 0..31
    const int n = blockIdx.z;   // batch, 0..7
    if (l >= LL) return;
    const int h = l / WW;
    const int w = l - h * WW;

    // Load this location's 9 weights into registers (coalesced: stride L between taps).
    const float* wp = wt + (((size_t)n * CW + g) * 9) * LL + l;
    float w9[9];
#pragma unroll
    for (int kk = 0; kk < 9; ++kk) w9[kk] = wp[(size_t)kk * LL];

    // Precompute tap offsets + validity (zero padding of 1).
    int off[9];
    bool val[9];
#pragma unroll
    for (int kk = 0; kk < 9; ++kk) {
        const int hh = h + kk / 3 - 1;
        const int ww = w + kk % 3 - 1;
        val[kk] = ((unsigned)hh < (unsigned)HH) && ((unsigned)ww < (unsigned)WW);
        off[kk] = hh * WW + ww;
    }

    const int c0 = g * SHARE;
    const float* ip = in + ((size_t)n * CC + c0) * LL;
    float* op = out + ((size_t)n * CC + c0) * LL;
#pragma unroll
    for (int s = 0; s < SHARE; ++s) {
        float acc = 0.f;
#pragma unroll
        for (int kk = 0; kk < 9; ++kk) {
            const float v = val[kk] ? ip[(size_t)s * LL + off[kk]] : 0.f;
            acc = fmaf(v, w9[kk], acc);
        }
        op[(size_t)s * LL + l] = acc;
    }
}

extern "C" void kernel_launch(void* const* d_in, const int* in_sizes, int n_in,
                              void* d_out, int out_size, void* d_ws, size_t ws_size,
                              hipStream_t stream) {
    const float* in = (const float*)d_in[0];
    const float* wt = (const float*)d_in[1];
    float* out = (float*)d_out;
    dim3 grid((LL + 255) / 256, CW, NN);
    agg_kernel<<<grid, 256, 0, stream>>>(in, wt, out);
}